// Round 3
// baseline (220.907 us; speedup 1.0000x reference)
//
#include <hip/hip_runtime.h>

// SmoothTopKGate: per row of 8 floats, solve sum_i sigmoid((s_i - theta)/tau) = k
// (k=2, tau=0.01) by safeguarded Newton, then emit the sigmoids.
//
// R3: 5 -> 3 Newton updates (init = midpoint of t2,t3 is EXACT for the
// 2-active-element case; worst-case tie analysis puts the root within
// ~1.2*tau and 3 updates converge residual to <~1e-3 -> output err ~5e-3,
// well under the 2e-2 threshold with the reference's own 3.9e-3 residual).
// Work in the x*C scaled domain (saves per-iter theta*C). Top-2/3 selection
// via quad-merge med3/max3 network (24 ops vs 40-op insertion).
//
// NOTE (correctness trap, do not "optimize"): g must be accumulated as
// fmaf(m, 1-m, g), NOT as f+2-sum(m^2). The latter cancels to exactly 0 for
// gap ~40*tau rows while f~2e-9, and the floored denominator then slams
// theta to the clamp bound -> absmax ~0.95.

__global__ __launch_bounds__(256) void smooth_topk_kernel(
    const float* __restrict__ s, float* __restrict__ out, int nrows) {
  int row = blockIdx.x * blockDim.x + threadIdx.x;
  if (row >= nrows) return;

  const float4* sp = reinterpret_cast<const float4*>(s) + (size_t)row * 2;
  float4 a4 = sp[0];
  float4 b4 = sp[1];

  const float C = 144.26950408889634f;  // 1/(tau*ln2), tau = 0.01
  float vc[8] = {a4.x * C, a4.y * C, a4.z * C, a4.w * C,
                 b4.x * C, b4.y * C, b4.z * C, b4.w * C};

  // ---- top-2 and top-3 of vc[0..7] (scaled domain), quad-merge network ----
  // quad 0: vc[0..3]
  float a = fmaxf(vc[0], vc[1]), b = fminf(vc[0], vc[1]);
  float c = fmaxf(vc[2], vc[3]), d = fminf(vc[2], vc[3]);
  float minac = fminf(a, c);
  float p1 = fmaxf(a, c);
  float p2 = fmaxf(minac, fmaxf(b, d));
  float p3 = __builtin_amdgcn_fmed3f(b, d, minac);  // 3rd largest of quad
  // quad 1: vc[4..7]
  float e = fmaxf(vc[4], vc[5]), f_ = fminf(vc[4], vc[5]);
  float g = fmaxf(vc[6], vc[7]), h = fminf(vc[6], vc[7]);
  float mineg = fminf(e, g);
  float q1 = fmaxf(e, g);
  float q2 = fmaxf(mineg, fmaxf(f_, h));
  float q3 = __builtin_amdgcn_fmed3f(f_, h, mineg);
  // merge triples: need 2nd and 3rd of union only
  float t2 = fmaxf(fminf(p1, q1), fmaxf(p2, q2));                      // 2nd
  float t3 = fmaxf(fmaxf(fminf(p2, q1), fminf(p1, q2)), fmaxf(p3, q3));// 3rd

  float phi = 0.5f * (t2 + t3);   // scaled theta; exact 2-element root
  const float lo = t3 - 4.33f;    // 0.03/ (tau*ln2) -- root provably inside
  const float hi = t2 + 4.33f;

#pragma unroll
  for (int it = 0; it < 3; ++it) {
    float f = -2.0f;  // sum(m) - k
    float gg = 0.0f;  // sum(m*(1-m))
#pragma unroll
    for (int i = 0; i < 8; ++i) {
      float ex = __builtin_amdgcn_exp2f(phi - vc[i]);  // inf below theta, 0 above
      float m = __builtin_amdgcn_rcpf(1.0f + ex);      // rcp(inf)=0: no NaN
      f += m;
      gg = fmaf(m, 1.0f - m, gg);                      // m=0 -> exactly 0
    }
    // scaled newton step: d(phi) = C*tau * f/g = f/(g*ln2)
    float step = f * 1.4426950408889634f * __builtin_amdgcn_rcpf(fmaxf(gg, 1e-12f));
    phi = fminf(fmaxf(phi + step, lo), hi);
  }

  float o[8];
#pragma unroll
  for (int i = 0; i < 8; ++i) {
    float ex = __builtin_amdgcn_exp2f(phi - vc[i]);
    o[i] = __builtin_amdgcn_rcpf(1.0f + ex);
  }
  float4* op = reinterpret_cast<float4*>(out) + (size_t)row * 2;
  op[0] = make_float4(o[0], o[1], o[2], o[3]);
  op[1] = make_float4(o[4], o[5], o[6], o[7]);
}

extern "C" void kernel_launch(void* const* d_in, const int* in_sizes, int n_in,
                              void* d_out, int out_size, void* d_ws, size_t ws_size,
                              hipStream_t stream) {
  const float* s = (const float*)d_in[0];
  float* out = (float*)d_out;
  int nrows = in_sizes[0] / 8;  // S_DIM = 8
  int block = 256;
  int grid = (nrows + block - 1) / block;
  smooth_topk_kernel<<<grid, block, 0, stream>>>(s, out, nrows);
}

// Round 4
// 211.957 us; speedup vs baseline: 1.0422x; 1.0422x over previous
//
#include <hip/hip_runtime.h>

// SmoothTopKGate: per row of 8 floats, solve sum_i sigmoid((s_i - theta)/tau) = k
// (k=2, tau=0.01) by safeguarded Newton, then emit the sigmoids.
//
// R4: TWO LANES PER ROW. R3 showed dur pinned at 79us with VALU 38% / HBM 30%
// (latency-bound, not throughput): 1-thread-per-row float4 accesses are
// 32B-strided, so every dwordx4 touches 32 cache lines at half occupancy.
// Now each lane owns one contiguous float4 (wave = 1KB contiguous burst both
// directions); lane pairs cooperate via __shfl_xor(.,1) (DPP quad_perm, no
// LDS): exchange quad top-3 (3 shuffles) and per-iteration partial f/g sums
// (2 shuffles x 3 iters). Both lanes compute bit-identical theta (commutative
// adds), so the pair never diverges.
//
// NOTE (correctness trap, do not "optimize"): g must be accumulated as
// fmaf(m, 1-m, g), NOT as f+2-sum(m^2) — catastrophic cancellation for
// ~40*tau gaps slams theta to the clamp bound (absmax ~0.95).

__global__ __launch_bounds__(256) void smooth_topk_kernel(
    const float* __restrict__ s, float* __restrict__ out, int nhalf) {
  int gid = blockIdx.x * blockDim.x + threadIdx.x;  // one float4 (half-row) each
  if (gid >= nhalf) return;

  const float C = 144.26950408889634f;  // 1/(tau*ln2), tau = 0.01

  float4 v4 = reinterpret_cast<const float4*>(s)[gid];
  float v0 = v4.x * C, v1 = v4.y * C, v2 = v4.z * C, v3 = v4.w * C;

  // ---- top-3 of my quad (p1 >= p2 >= p3), scaled domain ----
  float a = fmaxf(v0, v1), b = fminf(v0, v1);
  float c = fmaxf(v2, v3), d = fminf(v2, v3);
  float mn = fminf(a, c);
  float p1 = fmaxf(a, c);
  float p2 = fmaxf(mn, fmaxf(b, d));
  float p3 = __builtin_amdgcn_fmed3f(b, d, mn);

  // ---- partner quad's top-3 via xor-1 shuffle (DPP quad_perm) ----
  float q1 = __shfl_xor(p1, 1, 64);
  float q2 = __shfl_xor(p2, 1, 64);
  float q3 = __shfl_xor(p3, 1, 64);

  // 2nd and 3rd largest of the union (symmetric in p<->q: both lanes agree)
  float t2 = fmaxf(fminf(p1, q1), fmaxf(p2, q2));
  float t3 = fmaxf(fmaxf(fminf(p2, q1), fminf(p1, q2)), fmaxf(p3, q3));

  float phi = 0.5f * (t2 + t3);   // scaled theta; exact for 2-active case
  const float lo = t3 - 4.33f;    // root provably within ~0.025/tau scaled
  const float hi = t2 + 4.33f;

#pragma unroll
  for (int it = 0; it < 3; ++it) {
    float e0 = __builtin_amdgcn_exp2f(phi - v0);
    float e1 = __builtin_amdgcn_exp2f(phi - v1);
    float e2 = __builtin_amdgcn_exp2f(phi - v2);
    float e3 = __builtin_amdgcn_exp2f(phi - v3);
    float m0 = __builtin_amdgcn_rcpf(1.0f + e0);  // rcp(inf)=0: no NaN
    float m1 = __builtin_amdgcn_rcpf(1.0f + e1);
    float m2 = __builtin_amdgcn_rcpf(1.0f + e2);
    float m3 = __builtin_amdgcn_rcpf(1.0f + e3);
    float fh = (m0 + m1) + (m2 + m3);             // my half's sum(m)
    float gh = fmaf(m0, 1.0f - m0, fmaf(m1, 1.0f - m1,
               fmaf(m2, 1.0f - m2, m3 * (1.0f - m3))));
    float f = (fh + __shfl_xor(fh, 1, 64)) - 2.0f;  // commutative: lanes agree
    float g = gh + __shfl_xor(gh, 1, 64);
    float step = f * 1.4426950408889634f * __builtin_amdgcn_rcpf(fmaxf(g, 1e-12f));
    phi = fminf(fmaxf(phi + step, lo), hi);
  }

  float4 o;
  o.x = __builtin_amdgcn_rcpf(1.0f + __builtin_amdgcn_exp2f(phi - v0));
  o.y = __builtin_amdgcn_rcpf(1.0f + __builtin_amdgcn_exp2f(phi - v1));
  o.z = __builtin_amdgcn_rcpf(1.0f + __builtin_amdgcn_exp2f(phi - v2));
  o.w = __builtin_amdgcn_rcpf(1.0f + __builtin_amdgcn_exp2f(phi - v3));
  reinterpret_cast<float4*>(out)[gid] = o;
}

extern "C" void kernel_launch(void* const* d_in, const int* in_sizes, int n_in,
                              void* d_out, int out_size, void* d_ws, size_t ws_size,
                              hipStream_t stream) {
  const float* s = (const float*)d_in[0];
  float* out = (float*)d_out;
  int nhalf = in_sizes[0] / 4;  // number of float4 half-rows (2 per row)
  int block = 256;
  int grid = (nhalf + block - 1) / block;
  smooth_topk_kernel<<<grid, block, 0, stream>>>(s, out, nhalf);
}